// Round 9
// baseline (3503.358 us; speedup 1.0000x reference)
//
#include <hip/hip_runtime.h>
#include <hip/hip_bf16.h>

#define DD 32
#define CC 128
#define N1 1024   // 2*H
#define ROWS 32
#define NBLK 64
#define THREADS 512

#define FPW 172   // frags/wave/eval: 40 L1 (theta+ctx) + 128 L2 + 4 L3
#define NG  43    // groups of 4 frags; slots = g&3, lookahead 3, W(vmcnt 8)

typedef float f32x4 __attribute__((ext_vector_type(4)));
typedef __bf16 bf16x8 __attribute__((ext_vector_type(8)));
typedef unsigned short u16x4 __attribute__((ext_vector_type(4)));

#define STREAM_OFF 0
#define STREAM_SZ (8*FPW*1024)   // 1,409,024 B per copy

static __device__ __forceinline__ unsigned short f2bfu(float f) {
    __hip_bfloat16 h = __float2bfloat16(f);
    unsigned short u; __builtin_memcpy(&u, &h, 2); return u;
}
static __device__ __forceinline__ float bfu2f(unsigned short u) {
    unsigned int x = ((unsigned int)u) << 16;
    float f; __builtin_memcpy(&f, &x, 4); return f;
}

// per-wave consumption-order stream pack, replicated ncopy times.
// seq<40: L1 kt-major (kt5=0 theta W1[0:32], kt5=1..4 ctx W1[33+32*(kt5-1)..]);
// seq<168: L2 kt-major; else L3 (wave -> nt3=wv&1, kq=wv>>1).
__global__ void pack_stream(const float* __restrict__ W1, const float* __restrict__ W2,
                            const float* __restrict__ W3, __bf16* __restrict__ dst) {
    int copy = blockIdx.x / (8 * FPW);
    int g = blockIdx.x % (8 * FPW);
    int lane = threadIdx.x;
    int wv = g / FPW, seq = g % FPW;
    const float* W; int Kreal, N, kt, nt;
    if (seq < 40) {
        int kt5 = seq >> 3, j = seq & 7;
        nt = wv * 4 + (j >> 1) + 32 * (j & 1);
        N = N1;
        if (kt5 == 0) { W = W1;           Kreal = 32;  kt = 0; }
        else          { W = W1 + 33 * N1; Kreal = 128; kt = kt5 - 1; }
    } else if (seq < 168) {
        int s2 = seq - 40; int j = s2 & 7;
        kt = s2 >> 3;
        nt = wv * 4 + (j >> 1) + 32 * (j & 1);
        W = W2; Kreal = 512; N = N1;
    } else {
        int q = seq - 168;
        kt = (wv >> 1) * 4 + q; nt = wv & 1;
        W = W3; Kreal = 512; N = DD;
    }
    int kbase = kt * 32 + (lane >> 4) * 8;
    int n = nt * 16 + (lane & 15);
    union { unsigned short b[8]; int4 v; } u;
#pragma unroll
    for (int j = 0; j < 8; j++) {
        int k = kbase + j;
        float v = (k < Kreal) ? W[(size_t)k * N + n] : 0.f;
        u.b[j] = f2bfu(v);
    }
    unsigned short* d = (unsigned short*)dst + (size_t)copy * (STREAM_SZ / 2) + (size_t)g * 512;
    *reinterpret_cast<int4*>(d + lane * 8) = u.v;
}

#define MFMA(a, b, c) __builtin_amdgcn_mfma_f32_16x16x32_bf16((a), (b), (c), 0, 0, 0)
#define BC(x) __builtin_bit_cast(bf16x8, (x))

#define LOADG(dst, f) \
    asm volatile("global_load_dwordx4 %0, %1, off" \
                 : "=v"(dst) : "v"(stream_lane + (size_t)(f) * 1024))

// issue group gg (compile-time, 0..42) into slot gg&3; frags 4*gg..4*gg+3
#define ISSUE(gg) do { \
    LOADG(ga[(gg) & 3][0], 4 * (gg) + 0); \
    LOADG(ga[(gg) & 3][1], 4 * (gg) + 1); \
    LOADG(ga[(gg) & 3][2], 4 * (gg) + 2); \
    LOADG(ga[(gg) & 3][3], 4 * (gg) + 3); \
} while (0)

#define SBAR() __builtin_amdgcn_sched_barrier(0)
// steady state: outstanding {g, g+1, g+2} = 12 loads; wait to 8 -> group g complete
#define W8() do { asm volatile("s_waitcnt vmcnt(8)" ::: "memory"); \
                  __builtin_amdgcn_sched_barrier(0); } while (0)
// block barrier WITHOUT vmcnt drain (in-flight VGPR weight loads survive)
#define BARRIER() asm volatile("s_waitcnt lgkmcnt(0)\n\ts_barrier" ::: "memory")

__global__ __launch_bounds__(THREADS, 2)
void ccnf_main(const float* __restrict__ theta0,
               const float* __restrict__ ctx,
               const float* __restrict__ W1,
               const float* __restrict__ b1g,
               const float* __restrict__ b2g,
               const float* __restrict__ b3g,
               const char* __restrict__ wsb,
               const int* __restrict__ nsteps_p,
               float* __restrict__ out, int copyMask)
{
    // LDS: hbuf1 32K + hbuf2 32K + als 10K + biases 6K = 80 KB (1 block/CU)
    __shared__ __align__(16) unsigned short hbuf1[16 * 1024];  // [kt][kg4][row32][8]
    __shared__ __align__(16) unsigned short hbuf2[16 * 1024];
    __shared__ __align__(16) unsigned short als[5 * 1024];     // x | ctx0..3, same layout
    __shared__ __align__(16) unsigned short b1s[N1], wts[N1], b2s[N1];
    float* kpart = reinterpret_cast<float*>(hbuf1);            // [kq4][row32][32] XOR granules

    const int tid  = threadIdx.x;
    const int lane = tid & 63;
    const int wv   = tid >> 6;
    const int row0 = blockIdx.x * ROWS;
    const int r16  = lane & 15;
    const int wq   = lane >> 4;
    const int rb4  = wq * 4;

    const char* stream_lane = wsb + STREAM_OFF
        + (size_t)(blockIdx.x & copyMask) * STREAM_SZ
        + (size_t)wv * FPW * 1024 + lane * 16;

    // ---- prologue: biases, ctx, theta -> LDS ----
    for (int i = tid; i < N1; i += THREADS) {
        b1s[i] = f2bfu(b1g[i]);
        wts[i] = f2bfu(W1[32 * N1 + i]);
        b2s[i] = f2bfu(b2g[i]);
    }
#pragma unroll
    for (int j = 0; j < 8; ++j) {
        int e = j * 512 + tid;                  // 32 rows x 128 cols
        int r = e >> 7, c = e & 127;
        als[1024 + (c >> 5) * 1024 + ((c & 31) >> 3) * 256 + r * 8 + (c & 7)]
            = f2bfu(ctx[(size_t)(row0 + r) * CC + c]);
    }
    float th[2], acck[2];
#pragma unroll
    for (int j = 0; j < 2; ++j) {
        int e = j * 512 + tid;                  // thread owns elems e: row=e>>5, d=e&31
        th[j] = theta0[(size_t)row0 * DD + e];
        acck[j] = 0.f;
        int r = e >> 5, d = e & 31;
        als[(d >> 3) * 256 + r * 8 + (d & 7)] = f2bfu(th[j]);
    }
    const int nt3 = wv & 1, kq = wv >> 1;
    const float4 b3r = *reinterpret_cast<const float4*>(&b3g[nt3 * 16 + rb4]);
    const int nst = nsteps_p[0];
    const float dt = 1.0f / (float)nst;
    __syncthreads();

    // ---- warm pipeline: groups 0,1,2 (12 loads in flight) ----
    f32x4 ga[4][4];
    asm volatile("s_waitcnt vmcnt(0)" ::: "memory");
    ISSUE(0); ISSUE(1); ISSUE(2);

    f32x4 acc[4][2][2];

    for (int step = 0; step < nst; ++step) {
        float tb = (float)step * dt;
#pragma unroll 1
        for (int s = 0; s < 4; ++s) {
            float tt = tb + ((s == 0) ? 0.f : (s == 3) ? dt : 0.5f * dt);

            // ---- zero acc ----
#pragma unroll
            for (int p = 0; p < 4; ++p)
#pragma unroll
                for (int ab = 0; ab < 2; ++ab)
#pragma unroll
                    for (int rt = 0; rt < 2; ++rt) {
                        f32x4 z = {0.f, 0.f, 0.f, 0.f}; acc[p][ab][rt] = z;
                    }

            // ---- L1: groups 0..9 (kt5 = g>>1: theta, ctx0..3; h = g&1) ----
#pragma unroll
            for (int g = 0; g < 10; ++g) {
                W8();
                const int kt5 = g >> 1, h = g & 1, sl = g & 3;
                const unsigned short* bs = als + kt5 * 1024 + wq * 256 + r16 * 8;
#pragma unroll
                for (int rt = 0; rt < 2; ++rt) {
                    bf16x8 hf = *reinterpret_cast<const bf16x8*>(bs + rt * 128);
                    acc[2*h+0][0][rt] = MFMA(BC(ga[sl][0]), hf, acc[2*h+0][0][rt]);
                    acc[2*h+0][1][rt] = MFMA(BC(ga[sl][1]), hf, acc[2*h+0][1][rt]);
                    acc[2*h+1][0][rt] = MFMA(BC(ga[sl][2]), hf, acc[2*h+1][0][rt]);
                    acc[2*h+1][1][rt] = MFMA(BC(ga[sl][3]), hf, acc[2*h+1][1][rt]);
                }
                SBAR();
                ISSUE(g + 3);   // max 12 < 43, no wrap
            }
            // L1 epilogue: GLU(+b1 + t*w1t) -> hbuf1
#pragma unroll
            for (int p = 0; p < 4; ++p) {
                const int nt = wv * 4 + p;
                const int nA = nt * 16 + rb4;
                u16x4 b1A = *reinterpret_cast<const u16x4*>(&b1s[nA]);
                u16x4 wtA = *reinterpret_cast<const u16x4*>(&wts[nA]);
                u16x4 b1B = *reinterpret_cast<const u16x4*>(&b1s[nA + 512]);
                u16x4 wtB = *reinterpret_cast<const u16x4*>(&wts[nA + 512]);
#pragma unroll
                for (int rt = 0; rt < 2; ++rt) {
                    int row = rt * 16 + r16;
                    u16x4 o;
#pragma unroll
                    for (int i = 0; i < 4; ++i) {
                        float va = acc[p][0][rt][i] + bfu2f(b1A[i]) + tt * bfu2f(wtA[i]);
                        float vb = acc[p][1][rt][i] + bfu2f(b1B[i]) + tt * bfu2f(wtB[i]);
                        o[i] = f2bfu(va * (1.f / (1.f + __expf(-vb))));
                    }
                    *reinterpret_cast<u16x4*>(
                        &hbuf1[(nt >> 1) * 1024 + ((nt & 1) * 2 + (wq >> 1)) * 256
                               + row * 8 + (wq & 1) * 4]) = o;
                }
            }
            BARRIER();   // h1 ready

            // ---- zero acc ----
#pragma unroll
            for (int p = 0; p < 4; ++p)
#pragma unroll
                for (int ab = 0; ab < 2; ++ab)
#pragma unroll
                    for (int rt = 0; rt < 2; ++rt) {
                        f32x4 z = {0.f, 0.f, 0.f, 0.f}; acc[p][ab][rt] = z;
                    }

            // ---- L2: groups 10..41 (kt = (g-10)>>1, h = g&1) ----
#pragma unroll
            for (int g = 10; g < 42; ++g) {
                W8();
                const int kt = (g - 10) >> 1, h = g & 1, sl = g & 3;
                const unsigned short* bs = hbuf1 + kt * 1024 + wq * 256 + r16 * 8;
#pragma unroll
                for (int rt = 0; rt < 2; ++rt) {
                    bf16x8 hf = *reinterpret_cast<const bf16x8*>(bs + rt * 128);
                    acc[2*h+0][0][rt] = MFMA(BC(ga[sl][0]), hf, acc[2*h+0][0][rt]);
                    acc[2*h+0][1][rt] = MFMA(BC(ga[sl][1]), hf, acc[2*h+0][1][rt]);
                    acc[2*h+1][0][rt] = MFMA(BC(ga[sl][2]), hf, acc[2*h+1][0][rt]);
                    acc[2*h+1][1][rt] = MFMA(BC(ga[sl][3]), hf, acc[2*h+1][1][rt]);
                }
                SBAR();
                const int gi = (g + 3 < NG) ? (g + 3) : (g + 3 - NG);  // 43->0', 44->1'
                ISSUE(gi);
            }
            // L2 epilogue: GLU(+b2) -> hbuf2
#pragma unroll
            for (int p = 0; p < 4; ++p) {
                const int nt = wv * 4 + p;
                const int nA = nt * 16 + rb4;
                u16x4 b2A = *reinterpret_cast<const u16x4*>(&b2s[nA]);
                u16x4 b2B = *reinterpret_cast<const u16x4*>(&b2s[nA + 512]);
#pragma unroll
                for (int rt = 0; rt < 2; ++rt) {
                    int row = rt * 16 + r16;
                    u16x4 o;
#pragma unroll
                    for (int i = 0; i < 4; ++i) {
                        float va = acc[p][0][rt][i] + bfu2f(b2A[i]);
                        float vb = acc[p][1][rt][i] + bfu2f(b2B[i]);
                        o[i] = f2bfu(va * (1.f / (1.f + __expf(-vb))));
                    }
                    *reinterpret_cast<u16x4*>(
                        &hbuf2[(nt >> 1) * 1024 + ((nt & 1) * 2 + (wq >> 1)) * 256
                               + row * 8 + (wq & 1) * 4]) = o;
                }
            }
            BARRIER();   // h2 ready; hbuf1 now dead -> kpart may overwrite

            // ---- L3: group 42 (slot 2); kpart (aliased hbuf1) ----
            {
                W8();    // outstanding {42, 0', 1'} -> 42 complete
                f32x4 a3[2];
#pragma unroll
                for (int rt = 0; rt < 2; ++rt) { f32x4 z = {0.f,0.f,0.f,0.f}; a3[rt] = z; }
#pragma unroll
                for (int q = 0; q < 4; ++q) {
                    const int kt3 = kq * 4 + q;
                    const unsigned short* bs = hbuf2 + kt3 * 1024 + wq * 256 + r16 * 8;
#pragma unroll
                    for (int rt = 0; rt < 2; ++rt) {
                        bf16x8 hf = *reinterpret_cast<const bf16x8*>(bs + rt * 128);
                        a3[rt] = MFMA(BC(ga[2][q]), hf, a3[rt]);
                    }
                }
                SBAR();
                ISSUE(2);   // next-eval group 2 (frags 8..11); slot 2 just freed
#pragma unroll
                for (int rt = 0; rt < 2; ++rt) {
                    int row = rt * 16 + r16;
                    float4 kv4;
                    kv4.x = a3[rt][0] + ((kq == 0) ? b3r.x : 0.f);
                    kv4.y = a3[rt][1] + ((kq == 0) ? b3r.y : 0.f);
                    kv4.z = a3[rt][2] + ((kq == 0) ? b3r.z : 0.f);
                    kv4.w = a3[rt][3] + ((kq == 0) ? b3r.w : 0.f);
                    int gsw = (nt3 * 4 + wq) ^ (row & 7);   // granule XOR: 2-way max
                    *reinterpret_cast<float4*>(&kpart[kq * 1024 + row * 32 + gsw * 4]) = kv4;
                }
            }
            BARRIER();   // kpart ready

            // ---- RK4 combine: thread owns elems e = j*512+tid ----
#pragma unroll
            for (int j = 0; j < 2; ++j) {
                int e = j * 512 + tid;
                int row = e >> 5, d = e & 31;
                float kv = 0.f;
#pragma unroll
                for (int k2 = 0; k2 < 4; ++k2)
                    kv += kpart[k2 * 1024 + row * 32 + (((d >> 2) ^ (row & 7)) << 2) + (d & 3)];
                float xe;
                if (s == 0)      { acck[j] = kv;          xe = th[j] + 0.5f * dt * kv; }
                else if (s == 1) { acck[j] += 2.f * kv;   xe = th[j] + 0.5f * dt * kv; }
                else if (s == 2) { acck[j] += 2.f * kv;   xe = th[j] + dt * kv; }
                else             { th[j] += (dt / 6.f) * (acck[j] + kv); xe = th[j]; }
                als[(d >> 3) * 256 + row * 8 + (d & 7)] = f2bfu(xe);
            }
            BARRIER();   // x ready; hbuf1 free for next L1
        }
    }
#pragma unroll
    for (int j = 0; j < 2; ++j)
        out[(size_t)row0 * DD + j * 512 + tid] = th[j];
}

extern "C" void kernel_launch(void* const* d_in, const int* in_sizes, int n_in,
                              void* d_out, int out_size, void* d_ws, size_t ws_size,
                              hipStream_t stream) {
    const float* theta0 = (const float*)d_in[0];
    const float* ctx    = (const float*)d_in[1];
    const float* W1     = (const float*)d_in[2];
    const float* b1     = (const float*)d_in[3];
    const float* W2     = (const float*)d_in[4];
    const float* b2     = (const float*)d_in[5];
    const float* W3     = (const float*)d_in[6];
    const float* b3     = (const float*)d_in[7];
    const int*   nst    = (const int*)d_in[8];
    float* out = (float*)d_out;
    char*  ws  = (char*)d_ws;

    __bf16* wstream = (__bf16*)(ws + STREAM_OFF);

    // 2 stream copies: per-XCD footprint <= 2.8 MB (L2-resident), halves reader contention
    int ncopy = (ws_size >= (size_t)2 * STREAM_SZ) ? 2 : 1;
    int copyMask = ncopy - 1;

    pack_stream<<<ncopy * 8 * FPW, 64, 0, stream>>>(W1, W2, W3, wstream);

    ccnf_main<<<NBLK, THREADS, 0, stream>>>(theta0, ctx, W1, b1, b2, b3,
                                            (const char*)ws, nst, out, copyMask);
}

// Round 10
// 1467.797 us; speedup vs baseline: 2.3868x; 2.3868x over previous
//
#include <hip/hip_runtime.h>
#include <hip/hip_bf16.h>

#define THREADS 512
#define NBLK 256
#define NGRP 32
#define GROWS 64
#define IMGU (173*512)                       // ushorts per member image (173 KB)
#define H1OFF  (8*IMGU*2)                    // 1,417,216 B
#define H1SZ   (NGRP*64*1024)                // 2 MB   (32 groups x 64 frags)
#define KPOFF  (H1OFF + H1SZ)
#define KPSZ   (NGRP*8*4096)                 // 1 MB   (8 members x [64][32] bf16)
#define CNTOFF (KPOFF + KPSZ)                // 32 groups x 2 counters

typedef float f32x4 __attribute__((ext_vector_type(4)));
typedef __bf16 bf16x8 __attribute__((ext_vector_type(8)));
typedef unsigned short u16x4 __attribute__((ext_vector_type(4)));

static __device__ __forceinline__ unsigned short f2bfu(float f) {
    __hip_bfloat16 h = __float2bfloat16(f);
    unsigned short u; __builtin_memcpy(&u, &h, 2); return u;
}
static __device__ __forceinline__ float bfu2f(unsigned short u) {
    unsigned int x = ((unsigned int)u) << 16;
    float f; __builtin_memcpy(&f, &x, 4); return f;
}

#define MFMA(a, b, c) __builtin_amdgcn_mfma_f32_16x16x32_bf16((a), (b), (c), 0, 0, 0)
#define BC(x) __builtin_bit_cast(bf16x8, (x))
#define LOADG(dst, addr) \
    asm volatile("global_load_dwordx4 %0, %1, off" : "=v"(dst) : "v"(addr))
#define SBAR() __builtin_amdgcn_sched_barrier(0)

__global__ void zero_cnt(unsigned* c) { if (threadIdx.x < 64) c[threadIdx.x] = 0u; }

// Per-member weight image: 128 W2 frags | 32 W1c frags | 8 W1a frags | 4 W3 frags | vec block.
// Frag element: lane l, j -> W[k = kt*32 + (l>>4)*8 + j][n = ntg*16 + (l&15)]
__global__ void pack_members(const float* __restrict__ W1, const float* __restrict__ W2,
                             const float* __restrict__ W3, const float* __restrict__ b1,
                             const float* __restrict__ b2, const float* __restrict__ b3,
                             unsigned short* __restrict__ dst) {
    int b = blockIdx.x, m = b / 173, fi = b % 173, lane = threadIdx.x;
    unsigned short* base = dst + (size_t)m * IMGU;
    if (fi == 172) {   // vec block: w1tA|w1tB|b1A|b1B|b2A|b2B (64 u16 each) + b3 (32 f32)
        unsigned short* vb = base + 172 * 512;
        for (int i = lane; i < 384; i += 64) {
            int region = i >> 6, o = i & 63;
            int cA = m * 64 + o, cB = 512 + m * 64 + o;
            float v = 0.f;
            if (region == 0) v = W1[32 * 1024 + cA];
            else if (region == 1) v = W1[32 * 1024 + cB];
            else if (region == 2) v = b1[cA];
            else if (region == 3) v = b1[cB];
            else if (region == 4) v = b2[cA];
            else                  v = b2[cB];
            vb[i] = f2bfu(v);
        }
        if (lane < 32) ((float*)(vb + 384))[lane] = b3[lane];
        return;
    }
    const float* W; int kbase, n, N;
    if (fi < 128) {        // W2 slice frags: idx = kt*8 + ntl
        int kt = fi >> 3, ntl = fi & 7;
        int ntg = (ntl < 4) ? (m * 4 + ntl) : (32 + m * 4 + (ntl - 4));
        W = W2; N = 1024; kbase = kt * 32; n = ntg * 16 + (lane & 15);
    } else if (fi < 160) { // W1c frags: idx = ktc*8 + ntl (ctx rows 33..160)
        int fj = fi - 128, ktc = fj >> 3, ntl = fj & 7;
        int ntg = (ntl < 4) ? (m * 4 + ntl) : (32 + m * 4 + (ntl - 4));
        W = W1 + 33 * 1024; N = 1024; kbase = ktc * 32; n = ntg * 16 + (lane & 15);
    } else if (fi < 168) { // W1a frags: idx = ntl (theta rows 0..31)
        int ntl = fi - 160;
        int ntg = (ntl < 4) ? (m * 4 + ntl) : (32 + m * 4 + (ntl - 4));
        W = W1; N = 1024; kbase = 0; n = ntg * 16 + (lane & 15);
    } else {               // W3 frags: idx = ktl*2 + nt3 (K-slice rows m*64..)
        int fj = fi - 168, ktl = fj >> 1, nt3 = fj & 1;
        W = W3; N = 32; kbase = m * 64 + ktl * 32; n = nt3 * 16 + (lane & 15);
    }
    kbase += (lane >> 4) * 8;
    union { unsigned short s[8]; int4 v; } u;
#pragma unroll
    for (int j = 0; j < 8; j++) u.s[j] = f2bfu(W[(size_t)(kbase + j) * N + n]);
    *reinterpret_cast<int4*>(base + (size_t)fi * 512 + lane * 8) = u.v;
}

static __device__ __forceinline__ void group_sync(unsigned* c, unsigned tgt) {
    __syncthreads();
    if (threadIdx.x == 0) {
        __hip_atomic_fetch_add(c, 1u, __ATOMIC_RELEASE, __HIP_MEMORY_SCOPE_AGENT);
        int gd = 0;
        while (__hip_atomic_load(c, __ATOMIC_ACQUIRE, __HIP_MEMORY_SCOPE_AGENT) < tgt) {
            __builtin_amdgcn_s_sleep(2);
            if (++gd > (1 << 22)) break;   // safety valve: terminate, never hang
        }
    }
    __syncthreads();
}

__global__ __launch_bounds__(THREADS, 2)
void ccnf_main(const float* __restrict__ theta0,
               const float* __restrict__ ctx,
               char* __restrict__ wsb,
               const int* __restrict__ nsteps_p,
               float* __restrict__ out)
{
    // LDS: W2 128K | cxt1 16K | h2 8K | x 4K = 156 KB (1 block/CU)
    __shared__ __align__(16) unsigned short w2s[128 * 512];
    __shared__ __align__(16) unsigned short cxts[64 * 128];   // [row][zlocal]
    __shared__ __align__(16) unsigned short h2s[8 * 512];     // frag(ktl*4+rt)
    __shared__ __align__(16) unsigned short als[2048];        // x frags [d>>3][row][d&7]

    const int tid = threadIdx.x;
    const int lane = tid & 63, wv = tid >> 6;
    const int rt = wv & 3, nh = wv >> 2;            // wave -> (rowtile, n-half)
    const int r16 = lane & 15, wq = lane >> 4, rb4 = wq * 4;
    const int row = rt * 16 + r16;
    const int g = blockIdx.x & 31, m = blockIdx.x >> 5;
    const int row0 = g * GROWS;

    const unsigned short* img = (const unsigned short*)wsb + (size_t)m * IMGU;
    unsigned short* h1u = (unsigned short*)(wsb + H1OFF) + (size_t)g * (64 * 512);
    unsigned short* kpu = (unsigned short*)(wsb + KPOFF) + (size_t)g * (8 * 2048);
    unsigned* cnt = (unsigned*)(wsb + CNTOFF) + g * 2;
    const char* h1lane = (const char*)h1u + lane * 16;

    // ---- resident VGPR constants ----
    bf16x8 w1aA[2], w1aB[2], w3f[2];
    u16x4 w1tA[2], w1tB[2], b1A[2], b1B[2], b2A[2], b2B[2];
#pragma unroll
    for (int k = 0; k < 2; ++k) {
        w1aA[k] = *(const bf16x8*)(img + (160 + 2 * nh + k) * 512 + lane * 8);
        w1aB[k] = *(const bf16x8*)(img + (164 + 2 * nh + k) * 512 + lane * 8);
        w3f[k]  = *(const bf16x8*)(img + (168 + k * 2 + nh) * 512 + lane * 8);
        int cl = (2 * nh + k) * 16 + rb4;
        const unsigned short* vu = img + 172 * 512;
        w1tA[k] = *(const u16x4*)(vu + cl);       w1tB[k] = *(const u16x4*)(vu + 64 + cl);
        b1A[k]  = *(const u16x4*)(vu + 128 + cl); b1B[k]  = *(const u16x4*)(vu + 192 + cl);
        b2A[k]  = *(const u16x4*)(vu + 256 + cl); b2B[k]  = *(const u16x4*)(vu + 320 + cl);
    }
    const int rowc = tid >> 3, db = (tid & 7) * 4;
    const float4 b3v = *(const float4*)((const float*)(img + 172 * 512 + 384) + db);

    // ---- prologue: W1c -> LDS (transient), ctx staging, theta ----
#pragma unroll
    for (int q = 0; q < 4; ++q) {   // 32 W1c frags -> w2s[0..32)
        int idx = wv * 4 + q;
        __builtin_amdgcn_global_load_lds(
            (const __attribute__((address_space(1))) void*)((const char*)img + (size_t)(128 + idx) * 1024 + lane * 16),
            (__attribute__((address_space(3))) void*)(w2s + idx * 512), 16, 0, 0);
    }
    {   // ctx [64 rows][128] fp32 -> staging frags at w2s[32*512..]
        const float* cp = ctx + (size_t)(row0 + rowc) * 128 + (tid & 7) * 16;
        float4 v0 = ((const float4*)cp)[0], v1 = ((const float4*)cp)[1];
        float4 v2 = ((const float4*)cp)[2], v3 = ((const float4*)cp)[3];
        int c0 = (tid & 7) * 16;
        unsigned short* sb = w2s + 16384 + (c0 >> 5) * 2048 + ((c0 & 31) >> 3) * 512 + rowc * 8;
        u16x4 o;
        o[0]=f2bfu(v0.x); o[1]=f2bfu(v0.y); o[2]=f2bfu(v0.z); o[3]=f2bfu(v0.w); *(u16x4*)(sb) = o;
        o[0]=f2bfu(v1.x); o[1]=f2bfu(v1.y); o[2]=f2bfu(v1.z); o[3]=f2bfu(v1.w); *(u16x4*)(sb + 4) = o;
        o[0]=f2bfu(v2.x); o[1]=f2bfu(v2.y); o[2]=f2bfu(v2.z); o[3]=f2bfu(v2.w); *(u16x4*)(sb + 512) = o;
        o[0]=f2bfu(v3.x); o[1]=f2bfu(v3.y); o[2]=f2bfu(v3.z); o[3]=f2bfu(v3.w); *(u16x4*)(sb + 516) = o;
    }
    float th[4], acck[4];
    {
        float4 t0 = *(const float4*)(theta0 + (size_t)(row0 + rowc) * 32 + db);
        th[0]=t0.x; th[1]=t0.y; th[2]=t0.z; th[3]=t0.w;
        acck[0]=acck[1]=acck[2]=acck[3]=0.f;
        u16x4 xo; xo[0]=f2bfu(t0.x); xo[1]=f2bfu(t0.y); xo[2]=f2bfu(t0.z); xo[3]=f2bfu(t0.w);
        *(u16x4*)(als + (db >> 3) * 512 + rowc * 8 + (db & 7)) = xo;
    }
    const int nst = nsteps_p[0];
    const float dt = 1.0f / (float)nst;
    __syncthreads();

    // ---- cxt1 = ctx @ W1c-slice (pure product; b1 added later) ----
#pragma unroll
    for (int ab = 0; ab < 2; ++ab)
#pragma unroll
        for (int k = 0; k < 2; ++k) {
            int ntl = ab * 4 + 2 * nh + k;
            f32x4 a = {0.f, 0.f, 0.f, 0.f};
#pragma unroll
            for (int ktc = 0; ktc < 4; ++ktc) {
                bf16x8 cf = *(const bf16x8*)(w2s + 16384 + ktc * 2048 + wq * 512 + row * 8);
                bf16x8 wf = *(const bf16x8*)(w2s + (ktc * 8 + ntl) * 512 + lane * 8);
                a = MFMA(wf, cf, a);
            }
            u16x4 o;
#pragma unroll
            for (int i = 0; i < 4; ++i) o[i] = f2bfu(a[i]);
            *(u16x4*)(cxts + row * 128 + ab * 64 + (2 * nh + k) * 16 + rb4) = o;
        }
    __syncthreads();   // W1c/ctx staging consumed; w2s free

    // ---- W2 slice -> LDS (resident) ----
#pragma unroll
    for (int q = 0; q < 16; ++q) {
        int idx = wv * 16 + q;
        __builtin_amdgcn_global_load_lds(
            (const __attribute__((address_space(1))) void*)((const char*)img + (size_t)idx * 1024 + lane * 16),
            (__attribute__((address_space(3))) void*)(w2s + idx * 512), 16, 0, 0);
    }
    __syncthreads();

    // ---- main loop: 4*nst evals, 2 group-syncs each ----
    const int ne = 4 * nst;
    for (int e = 0; e < ne; ++e) {
        const int s = e & 3;
        const float tt = (float)(e >> 2) * dt + ((s == 0) ? 0.f : (s == 3) ? dt : 0.5f * dt);

        // === L1: z-slice = x@W1a + cxt1 + b1 + t*w1t; GLU -> global h1 frag(2m+nh, rt) ===
        {
            bf16x8 xf = *(const bf16x8*)(als + wq * 512 + row * 8);
            unsigned short* fb = h1u + ((2 * m + nh) * 4 + rt) * 512;
#pragma unroll
            for (int k = 0; k < 2; ++k) {
                f32x4 z = {0.f, 0.f, 0.f, 0.f};
                f32x4 zA = MFMA(w1aA[k], xf, z);
                f32x4 zB = MFMA(w1aB[k], xf, z);
                u16x4 cA = *(const u16x4*)(cxts + row * 128 + (2 * nh + k) * 16 + rb4);
                u16x4 cB = *(const u16x4*)(cxts + row * 128 + 64 + (2 * nh + k) * 16 + rb4);
                u16x4 o;
#pragma unroll
                for (int i = 0; i < 4; ++i) {
                    float va = zA[i] + bfu2f(cA[i]) + bfu2f(b1A[k][i]) + tt * bfu2f(w1tA[k][i]);
                    float vb = zB[i] + bfu2f(cB[i]) + bfu2f(b1B[k][i]) + tt * bfu2f(w1tB[k][i]);
                    o[i] = f2bfu(va * (1.f / (1.f + __expf(-vb))));
                }
                *(u16x4*)(fb + (k * 2 + (wq >> 1)) * 128 + r16 * 8 + (wq & 1) * 4) = o;
            }
        }
        group_sync(&cnt[0], 8u * (unsigned)(e + 1));   // h1 ready group-wide

        // === L2: stream 16 h1 B-frags (global), A = resident W2 (LDS) ===
        {
            f32x4 acc[4];
#pragma unroll
            for (int p = 0; p < 4; ++p) { f32x4 z = {0.f,0.f,0.f,0.f}; acc[p] = z; }
            f32x4 gb[4];
            LOADG(gb[0], h1lane + (0 * 4 + rt) * 1024);
            LOADG(gb[1], h1lane + (1 * 4 + rt) * 1024);
            LOADG(gb[2], h1lane + (2 * 4 + rt) * 1024);
            LOADG(gb[3], h1lane + (3 * 4 + rt) * 1024);
#pragma unroll
            for (int kt = 0; kt < 16; ++kt) {
                if (kt < 13)      asm volatile("s_waitcnt vmcnt(3)" ::: "memory");
                else if (kt == 13) asm volatile("s_waitcnt vmcnt(2)" ::: "memory");
                else if (kt == 14) asm volatile("s_waitcnt vmcnt(1)" ::: "memory");
                else               asm volatile("s_waitcnt vmcnt(0)" ::: "memory");
                SBAR();
                bf16x8 hf = BC(gb[kt & 3]);
                acc[0] = MFMA(*(const bf16x8*)(w2s + (kt * 8 + 2 * nh + 0) * 512 + lane * 8), hf, acc[0]);
                acc[1] = MFMA(*(const bf16x8*)(w2s + (kt * 8 + 2 * nh + 1) * 512 + lane * 8), hf, acc[1]);
                acc[2] = MFMA(*(const bf16x8*)(w2s + (kt * 8 + 4 + 2 * nh + 0) * 512 + lane * 8), hf, acc[2]);
                acc[3] = MFMA(*(const bf16x8*)(w2s + (kt * 8 + 4 + 2 * nh + 1) * 512 + lane * 8), hf, acc[3]);
                SBAR();
                if (kt < 12) LOADG(gb[kt & 3], h1lane + ((kt + 4) * 4 + rt) * 1024);
            }
            // GLU(+b2) -> h2s frag(nh*4+rt) (LDS, block-local)
#pragma unroll
            for (int k = 0; k < 2; ++k) {
                u16x4 o;
#pragma unroll
                for (int i = 0; i < 4; ++i) {
                    float va = acc[k][i] + bfu2f(b2A[k][i]);
                    float vb = acc[2 + k][i] + bfu2f(b2B[k][i]);
                    o[i] = f2bfu(va * (1.f / (1.f + __expf(-vb))));
                }
                *(u16x4*)(h2s + (nh * 4 + rt) * 512 + (k * 2 + (wq >> 1)) * 128 + r16 * 8 + (wq & 1) * 4) = o;
            }
        }
        __syncthreads();   // h2s ready

        // === L3: k-partial = h2-slice @ W3-slice -> global kpart[m] (bf16) ===
        {
            f32x4 a3 = {0.f, 0.f, 0.f, 0.f};
#pragma unroll
            for (int ktl = 0; ktl < 2; ++ktl) {
                bf16x8 hf = *(const bf16x8*)(h2s + (ktl * 4 + rt) * 512 + lane * 8);
                a3 = MFMA(w3f[ktl], hf, a3);
            }
            u16x4 o;
#pragma unroll
            for (int i = 0; i < 4; ++i) o[i] = f2bfu(a3[i]);
            *(u16x4*)(kpu + m * 2048 + row * 32 + nh * 16 + rb4) = o;
        }
        group_sync(&cnt[1], 8u * (unsigned)(e + 1));   // kparts ready group-wide

        // === RK4 combine (replicated in all members; x stays local) ===
        {
            float kv[4] = {b3v.x, b3v.y, b3v.z, b3v.w};
#pragma unroll
            for (int mm = 0; mm < 8; ++mm) {
                u16x4 q = *(const u16x4*)(kpu + mm * 2048 + rowc * 32 + db);
#pragma unroll
                for (int i = 0; i < 4; ++i) kv[i] += bfu2f(q[i]);
            }
            u16x4 xo;
#pragma unroll
            for (int i = 0; i < 4; ++i) {
                float xe;
                if (s == 0)      { acck[i] = kv[i];          xe = th[i] + 0.5f * dt * kv[i]; }
                else if (s == 1) { acck[i] += 2.f * kv[i];   xe = th[i] + 0.5f * dt * kv[i]; }
                else if (s == 2) { acck[i] += 2.f * kv[i];   xe = th[i] + dt * kv[i]; }
                else             { th[i] += (dt / 6.f) * (acck[i] + kv[i]); xe = th[i]; }
                xo[i] = f2bfu(xe);
            }
            *(u16x4*)(als + (db >> 3) * 512 + rowc * 8 + (db & 7)) = xo;
        }
        __syncthreads();   // x ready for next eval
    }

    if (m == 0) {
        float4 o; o.x = th[0]; o.y = th[1]; o.z = th[2]; o.w = th[3];
        *(float4*)(out + (size_t)(row0 + rowc) * 32 + db) = o;
    }
}

extern "C" void kernel_launch(void* const* d_in, const int* in_sizes, int n_in,
                              void* d_out, int out_size, void* d_ws, size_t ws_size,
                              hipStream_t stream) {
    const float* theta0 = (const float*)d_in[0];
    const float* ctx    = (const float*)d_in[1];
    const float* W1     = (const float*)d_in[2];
    const float* b1     = (const float*)d_in[3];
    const float* W2     = (const float*)d_in[4];
    const float* b2     = (const float*)d_in[5];
    const float* W3     = (const float*)d_in[6];
    const float* b3     = (const float*)d_in[7];
    const int*   nst    = (const int*)d_in[8];
    float* out = (float*)d_out;
    char*  ws  = (char*)d_ws;

    zero_cnt<<<1, 64, 0, stream>>>((unsigned*)(ws + CNTOFF));
    pack_members<<<8 * 173, 64, 0, stream>>>(W1, W2, W3, b1, b2, b3, (unsigned short*)ws);
    ccnf_main<<<NBLK, THREADS, 0, stream>>>(theta0, ctx, ws, nst, out);
}